// Round 12
// baseline (1097.894 us; speedup 1.0000x reference)
//
#include <hip/hip_runtime.h>
#include <hip/hip_bf16.h>

#define N_ROWS 65536
#define DIM    2048
#define NEXP   8
#define TOPK   2
#define CHUNKS 8                   // 8 x (64 lanes x f4) = one full 8KB row
#define DEPTH  4                   // ring depth: 4 KB in flight per wave
#define BLOCK  1024                // 16 waves/block
#define GRID   512                 // 2 blocks/CU = 32 waves/CU; 8 rows/wave exact

typedef float f4 __attribute__((ext_vector_type(4)));

// Final lever test: store-lag depth. RPW=1 row-stream with a 4-deep static
// ring (16 data VGPRs, same budget as R7's clean VGPR=64): loads run 4 chunks
// (4 KB) ahead of stores, vs R7's lag of 1. Fully unrolled so all ring
// indices are compile-time (rule #20: runtime-indexed arrays -> scratch).
// Precommit: neutral (210-225us) => declare roofline next round.
__global__ __launch_bounds__(BLOCK, 4) void moe_router_kernel(
    const float* __restrict__ x,
    const float* __restrict__ W,
    const float* __restrict__ b,
    float* __restrict__ out_vals,   // [N, 2] f32
    float* __restrict__ out_idx,    // [N, 2] written as f32
    float* __restrict__ out_x)      // [N, D] f32 (pass-through copy)
{
    __shared__ float sW[NEXP * DIM];   // 64 KiB

    const f4* W4 = (const f4*)W;
    f4* sW4 = (f4*)sW;
    for (int i = threadIdx.x; i < NEXP * DIM / 4; i += BLOCK)
        sW4[i] = W4[i];
    __syncthreads();

    const int lane   = threadIdx.x & 63;
    const int wave   = (int)((blockIdx.x * BLOCK + threadIdx.x) >> 6);
    const int nwaves = (GRID * BLOCK) >> 6;   // 8192

    const f4* x4 = (const f4*)x;
    f4* ox4 = (f4*)out_x;
    const int row_f4 = DIM / 4;   // 512 float4s per row

    for (int row = wave; row < N_ROWS; row += nwaves) {
        const size_t base = (size_t)row * row_f4 + lane;

        float acc[NEXP];
#pragma unroll
        for (int e = 0; e < NEXP; ++e) acc[e] = 0.0f;

        // prologue: fill the 4-deep ring (4 KB of loads in flight)
        f4 xq[DEPTH];
#pragma unroll
        for (int d = 0; d < DEPTH; ++d)
            xq[d] = x4[base + d * 64];

#pragma unroll
        for (int c = 0; c < CHUNKS; ++c) {
            const int slot = c & (DEPTH - 1);   // static after full unroll
            const f4 xv = xq[slot];
            const int col = c * 64 + lane;

            // store current chunk (lags its load by DEPTH chunks)
            ox4[base + c * 64] = xv;

            // FMA from registers + LDS W
#pragma unroll
            for (int e = 0; e < NEXP; ++e) {
                const f4 wv = sW4[e * row_f4 + col];
                acc[e] += xv.x * wv.x + xv.y * wv.y + xv.z * wv.z + xv.w * wv.w;
            }

            // refill the slot with chunk c+DEPTH (issued after last read of xv)
            if (c + DEPTH < CHUNKS)
                xq[slot] = x4[base + (c + DEPTH) * 64];
        }

        // Wave-wide butterfly reduce: every lane ends with the full dot product.
#pragma unroll
        for (int e = 0; e < NEXP; ++e) {
            float v = acc[e];
            v += __shfl_xor(v, 32, 64);
            v += __shfl_xor(v, 16, 64);
            v += __shfl_xor(v, 8, 64);
            v += __shfl_xor(v, 4, 64);
            v += __shfl_xor(v, 2, 64);
            v += __shfl_xor(v, 1, 64);
            acc[e] = v;
        }

        // Lane 0 finishes the row: bias, softmax over 8, top-2.
        if (lane == 0) {
            float lg[NEXP];
#pragma unroll
            for (int e = 0; e < NEXP; ++e) lg[e] = acc[e] + b[e];

            float mx = lg[0];
#pragma unroll
            for (int e = 1; e < NEXP; ++e) mx = fmaxf(mx, lg[e]);

            float p[NEXP];
            float sum = 0.0f;
#pragma unroll
            for (int e = 0; e < NEXP; ++e) { p[e] = __expf(lg[e] - mx); sum += p[e]; }
            const float inv = 1.0f / sum;

            // top-1: strict > keeps the lowest index on ties (jax.lax.top_k order)
            int i1 = 0;
#pragma unroll
            for (int e = 1; e < NEXP; ++e) if (lg[e] > lg[i1]) i1 = e;
            // top-2: lowest-index-first among the rest
            int i2 = (i1 == 0) ? 1 : 0;
#pragma unroll
            for (int e = 0; e < NEXP; ++e)
                if (e != i1 && e != i2 && lg[e] > lg[i2]) i2 = e;

            out_vals[row * 2 + 0] = p[i1] * inv;
            out_vals[row * 2 + 1] = p[i2] * inv;
            out_idx[row * 2 + 0]  = (float)i1;
            out_idx[row * 2 + 1]  = (float)i2;
        }
    }
}

extern "C" void kernel_launch(void* const* d_in, const int* in_sizes, int n_in,
                              void* d_out, int out_size, void* d_ws, size_t ws_size,
                              hipStream_t stream) {
    const float* x = (const float*)d_in[0];
    const float* W = (const float*)d_in[1];
    const float* b = (const float*)d_in[2];

    float* out = (float*)d_out;
    float* out_vals = out;                       // N*2
    float* out_idx  = out + (size_t)N_ROWS * 2;  // N*2
    float* out_x    = out + (size_t)N_ROWS * 4;  // N*D

    moe_router_kernel<<<GRID, BLOCK, 0, stream>>>(x, W, b, out_vals, out_idx, out_x);
}

// Round 13
// 216.983 us; speedup vs baseline: 5.0598x; 5.0598x over previous
//
#include <hip/hip_runtime.h>
#include <hip/hip_bf16.h>

#define N_ROWS 65536
#define DIM    2048
#define NEXP   8
#define TOPK   2
#define RPW    2                   // rows per wave per iteration
#define CHUNKS (DIM / (64 * 4))    // 8 float4-chunks per row per lane
#define BLOCK  1024                // 16 waves/block
#define GRID   512                 // 2 blocks/CU; 8192 waves; 4 iters each, exact

typedef float f4 __attribute__((ext_vector_type(4)));

// FINAL (R7 config, session best: 216.8us = 4.96 TB/s on 1.074 GB min traffic).
// Structure: LDS-staged f32 W (64 KiB), 1024-thr blocks -> 2 blocks/CU =
// 32 waves/CU (HW max), RPW=2 with a 1-chunk software pipeline, VGPR=64 clean.
// Session ledger: burst width (R9), stream count (R9), nt/L2-bypass (R11),
// deeper pipelines (R10/R12 -> spill past VGPR=64) all neutral or worse.
// launch_bounds rule (3x confirmed): (1024,4) -> VGPR=64 clean; (1024,8) ->
// VGPR=32 spill cliff.
__global__ __launch_bounds__(BLOCK, 4) void moe_router_kernel(
    const float* __restrict__ x,
    const float* __restrict__ W,
    const float* __restrict__ b,
    float* __restrict__ out_vals,   // [N, 2] f32
    float* __restrict__ out_idx,    // [N, 2] written as f32
    float* __restrict__ out_x)      // [N, D] f32 (pass-through copy)
{
    __shared__ float sW[NEXP * DIM];   // 64 KiB

    const f4* W4 = (const f4*)W;
    f4* sW4 = (f4*)sW;
    for (int i = threadIdx.x; i < NEXP * DIM / 4; i += BLOCK)
        sW4[i] = W4[i];
    __syncthreads();

    const int lane   = threadIdx.x & 63;
    const int wave   = (int)((blockIdx.x * BLOCK + threadIdx.x) >> 6);
    const int nwaves = (GRID * BLOCK) >> 6;

    const f4* x4 = (const f4*)x;
    f4* ox4 = (f4*)out_x;
    const int row_f4 = DIM / 4;   // 512 float4s per row

    for (int g = wave; g < N_ROWS / RPW; g += nwaves) {
        const int row0 = g * RPW;
        const size_t base0 = (size_t)row0 * row_f4 + lane;
        const size_t base1 = base0 + row_f4;

        float acc[RPW][NEXP];
#pragma unroll
        for (int r = 0; r < RPW; ++r)
#pragma unroll
            for (int e = 0; e < NEXP; ++e) acc[r][e] = 0.0f;

        // prologue: chunk 0 loads in flight
        f4 xv0 = x4[base0];
        f4 xv1 = x4[base1];

#pragma unroll 2
        for (int c = 0; c < CHUNKS; ++c) {
            const int d4 = c * 64 + lane;

            // prefetch next chunk (keeps >=2 chunks of loads outstanding)
            f4 xn0, xn1;
            if (c + 1 < CHUNKS) {
                xn0 = x4[base0 + (c + 1) * 64];
                xn1 = x4[base1 + (c + 1) * 64];
            }

            // store current chunk (fused pass-through copy) before the FMA block
            ox4[base0 + c * 64] = xv0;
            ox4[base1 + c * 64] = xv1;

#pragma unroll
            for (int e = 0; e < NEXP; ++e) {
                const f4 wv = sW4[e * row_f4 + d4];
                acc[0][e] += xv0.x * wv.x + xv0.y * wv.y + xv0.z * wv.z + xv0.w * wv.w;
                acc[1][e] += xv1.x * wv.x + xv1.y * wv.y + xv1.z * wv.z + xv1.w * wv.w;
            }

            xv0 = xn0;
            xv1 = xn1;
        }

        // Wave-wide butterfly reduce: every lane ends with the full dot product.
#pragma unroll
        for (int r = 0; r < RPW; ++r) {
#pragma unroll
            for (int e = 0; e < NEXP; ++e) {
                float v = acc[r][e];
                v += __shfl_xor(v, 32, 64);
                v += __shfl_xor(v, 16, 64);
                v += __shfl_xor(v, 8, 64);
                v += __shfl_xor(v, 4, 64);
                v += __shfl_xor(v, 2, 64);
                v += __shfl_xor(v, 1, 64);
                acc[r][e] = v;
            }
        }

        // Lanes 0..RPW-1 finish one row each: bias, softmax over 8, top-2.
        if (lane < RPW) {
            const int r = lane;
            float lg[NEXP];
#pragma unroll
            for (int e = 0; e < NEXP; ++e) lg[e] = acc[r][e] + b[e];

            float mx = lg[0];
#pragma unroll
            for (int e = 1; e < NEXP; ++e) mx = fmaxf(mx, lg[e]);

            float p[NEXP];
            float sum = 0.0f;
#pragma unroll
            for (int e = 0; e < NEXP; ++e) { p[e] = __expf(lg[e] - mx); sum += p[e]; }
            const float inv = 1.0f / sum;

            // top-1: strict > keeps the lowest index on ties (jax.lax.top_k order)
            int i1 = 0;
#pragma unroll
            for (int e = 1; e < NEXP; ++e) if (lg[e] > lg[i1]) i1 = e;
            // top-2: lowest-index-first among the rest
            int i2 = (i1 == 0) ? 1 : 0;
#pragma unroll
            for (int e = 0; e < NEXP; ++e)
                if (e != i1 && e != i2 && lg[e] > lg[i2]) i2 = e;

            const int row = row0 + r;
            out_vals[row * 2 + 0] = p[i1] * inv;
            out_vals[row * 2 + 1] = p[i2] * inv;
            out_idx[row * 2 + 0]  = (float)i1;
            out_idx[row * 2 + 1]  = (float)i2;
        }
    }
}

extern "C" void kernel_launch(void* const* d_in, const int* in_sizes, int n_in,
                              void* d_out, int out_size, void* d_ws, size_t ws_size,
                              hipStream_t stream) {
    const float* x = (const float*)d_in[0];
    const float* W = (const float*)d_in[1];
    const float* b = (const float*)d_in[2];

    float* out = (float*)d_out;
    float* out_vals = out;                       // N*2
    float* out_idx  = out + (size_t)N_ROWS * 2;  // N*2
    float* out_x    = out + (size_t)N_ROWS * 4;  // N*D

    moe_router_kernel<<<GRID, BLOCK, 0, stream>>>(x, W, b, out_vals, out_idx, out_x);
}